// Round 11
// baseline (291.997 us; speedup 1.0000x reference)
//
#include <hip/hip_runtime.h>
#include <hip/hip_bf16.h>
#include <stdint.h>

#define M_DIM 8192
#define IN_F  4096
#define OUT_F 4096
#define NFP   256
#define NTI8  32              // i8 byte-tiles (4096 B / 128 B)
#define NTT   36              // + 4 bf16 tail byte-tiles (512 B / 128 B)

typedef __attribute__((ext_vector_type(4)))  int   v4i;
typedef __attribute__((ext_vector_type(8)))  short short8;
typedef __attribute__((ext_vector_type(4)))  float f32x4;

__device__ __forceinline__ void stage16(const void* g, void* l) {
    __builtin_amdgcn_global_load_lds(
        (const __attribute__((address_space(1))) int*)g,
        (__attribute__((address_space(3))) int*)l,
        16, 0, 0);
}

#define SB() __builtin_amdgcn_sched_barrier(0)
#define BARRIER() do { SB(); __builtin_amdgcn_s_barrier(); SB(); } while (0)

// ---------------------------------------------------------------------------
// Kernel 1: per-row quantization, 4 rows per block (amortize omap build).
// ---------------------------------------------------------------------------
__global__ __launch_bounds__(256)
void quant_rows(const float* __restrict__ x,
                const int* __restrict__ ind,
                char* __restrict__ qx,
                __hip_bfloat16* __restrict__ acts,
                float* __restrict__ xscale)
{
    __shared__ short omap[IN_F];
    __shared__ float red[4];
    __shared__ float s_xs;

    const int t = threadIdx.x;

    #pragma unroll
    for (int i = 0; i < IN_F / 256; ++i) omap[t + i * 256] = -1;
    __syncthreads();
    omap[ind[t]] = (short)t;
    __syncthreads();

    short om[16];
    #pragma unroll
    for (int j = 0; j < 16; ++j) om[j] = omap[t * 16 + j];

    for (int r = 0; r < 4; ++r) {
        const int row = blockIdx.x * 4 + r;

        const float* xr = x + (size_t)row * IN_F + t * 16;
        float v[16];
        #pragma unroll
        for (int j = 0; j < 4; ++j) {
            float4 f = *(const float4*)(xr + j * 4);
            v[j*4+0] = f.x; v[j*4+1] = f.y; v[j*4+2] = f.z; v[j*4+3] = f.w;
        }

        float m_nz = 0.f;
        #pragma unroll
        for (int j = 0; j < 16; ++j) {
            float a = fabsf(v[j]);
            if (om[j] < 0) m_nz = fmaxf(m_nz, a);
        }
        #pragma unroll
        for (int off = 32; off > 0; off >>= 1)
            m_nz = fmaxf(m_nz, __shfl_down(m_nz, off));
        if ((t & 63) == 0) red[t >> 6] = m_nz;
        __syncthreads();
        if (t == 0) {
            float a = fmaxf(fmaxf(red[0], red[1]), fmaxf(red[2], red[3]));
            xscale[row] = a / 127.0f;
            s_xs = (a > 0.f) ? (a / 127.0f) : 1.0f;
        }
        __syncthreads();
        const float xs = s_xs;

        union { char c[16]; int4 q; } u;
        #pragma unroll
        for (int j = 0; j < 16; ++j) {
            if (om[j] >= 0) {
                acts[(size_t)row * NFP + om[j]] = __float2bfloat16(v[j] / xs);
                u.c[j] = 0;
            } else {
                float rr = rintf(v[j] / xs);          // half-to-even == jnp.round
                rr = fminf(fmaxf(rr, -128.f), 127.f);
                u.c[j] = (char)(int)rr;
            }
        }
        *(int4*)(qx + (size_t)row * IN_F + t * 16) = u.q;
    }
}

// ---------------------------------------------------------------------------
// Kernel 2: weight int32 -> int8 (exact) + outlier gather (verified).
// ---------------------------------------------------------------------------
__global__ __launch_bounds__(256)
void conv_w(const int* __restrict__ qw, const int* __restrict__ ind,
            char* __restrict__ qb, __hip_bfloat16* __restrict__ wob)
{
    const int n = blockIdx.x;
    const int t = threadIdx.x;
    const int* src = qw + (size_t)n * IN_F + t * 16;
    union { char c[16]; int4 q; } u;
    #pragma unroll
    for (int j = 0; j < 4; ++j) {
        int4 raw = *(const int4*)(src + j * 4);
        u.c[j*4+0] = (char)raw.x; u.c[j*4+1] = (char)raw.y;
        u.c[j*4+2] = (char)raw.z; u.c[j*4+3] = (char)raw.w;
    }
    *(int4*)(qb + (size_t)n * IN_F + t * 16) = u.q;
    wob[(size_t)n * NFP + t] = __float2bfloat16((float)qw[(size_t)n * IN_F + ind[t]]);
}

// ---------------------------------------------------------------------------
// Kernel 3: 256x256 GEMM, B IN REGISTERS (global->VGPR, dbuf bX/bY), A in a
// 3-buffer LDS rotation (96 KB, stage distance 2), 36 unified byte-tiles:
// 32 i8 (mfma_i32_16x16x64_i8, exact) + 4 bf16 tail (outliers pre-divided).
// Loop bodies monomorphic per dtype (R10 lesson); stage/load helpers branch
// on uniform T for addressing only. Per tile: 4 phases {4 ds_read_b128 |
// b-loads/A-stage | barrier | setprio(1) 16 MFMA setprio(0) | barrier};
// manual vmcnt only for global_load_lds (b-loads compiler-tracked).
// ---------------------------------------------------------------------------
#define LOADA(MB, KK) \
    { _Pragma("unroll") for (int i = 0; i < 4; ++i) \
        af[i] = *(const v4i*)&Abuf[(((MB)+i)*16 + fr)*128 + ((((KK)*64) + kq4*16) ^ rsw)]; }

#define BLOAD(T, KK, DST) { \
    const char* bb_ = ((T) < NTI8) ? bqbase + (size_t)(T) * 128 \
                                   : bbbase + (size_t)((T) - NTI8) * 128; \
    const size_t bst_ = ((T) < NTI8) ? (size_t)IN_F : (size_t)512; \
    _Pragma("unroll") for (int n = 0; n < 4; ++n) \
        DST[(KK)*4+n] = *(const v4i*)(bb_ + (KK)*64 + (size_t)(n*16) * bst_); }

#define MFMA_I8(MB, KK, BC) \
    { _Pragma("unroll") for (int i = 0; i < 4; ++i) \
      _Pragma("unroll") for (int n = 0; n < 4; ++n) \
        acci[(MB)+i][n] = __builtin_amdgcn_mfma_i32_16x16x64_i8( \
            af[i], BC[(KK)*4+n], acci[(MB)+i][n], 0, 0, 0); }

#define MFMA_BF(MB, KK, BC) \
    { _Pragma("unroll") for (int i = 0; i < 4; ++i) \
      _Pragma("unroll") for (int n = 0; n < 4; ++n) \
        accf[(MB)+i][n] = __builtin_amdgcn_mfma_f32_16x16x32_bf16( \
            __builtin_bit_cast(short8, af[i]), \
            __builtin_bit_cast(short8, BC[(KK)*4+n]), \
            accf[(MB)+i][n], 0, 0, 0); }

#define TILE(T, BC, BN_, MF) do { \
    const int c_ = (T) % 3; \
    const char* Abuf = smem + c_ * 32768 + wm * 16384; \
    /* P1 */ \
    LOADA(0, 0); \
    if ((T) + 2 < NTT) stA((T) + 2, 0, ((T) + 2) % 3); \
    if ((T) + 1 < NTT) BLOAD((T) + 1, 0, BN_); \
    BARRIER(); \
    __builtin_amdgcn_s_setprio(1); MF(0, 0, BC); __builtin_amdgcn_s_setprio(0); \
    BARRIER(); \
    /* P2 */ \
    LOADA(4, 0); \
    if ((T) + 2 < NTT) stA((T) + 2, 1, ((T) + 2) % 3); \
    if ((T) + 1 < NTT) BLOAD((T) + 1, 1, BN_); \
    BARRIER(); \
    __builtin_amdgcn_s_setprio(1); MF(4, 0, BC); __builtin_amdgcn_s_setprio(0); \
    BARRIER(); \
    /* P3 */ \
    LOADA(0, 1); \
    BARRIER(); \
    __builtin_amdgcn_s_setprio(1); MF(0, 1, BC); __builtin_amdgcn_s_setprio(0); \
    BARRIER(); \
    /* P4 */ \
    LOADA(4, 1); \
    BARRIER(); \
    __builtin_amdgcn_s_setprio(1); MF(4, 1, BC); __builtin_amdgcn_s_setprio(0); \
    SB(); \
    if ((T) <= NTT - 3)      asm volatile("s_waitcnt vmcnt(6)" ::: "memory"); \
    else if ((T) == NTT - 2) asm volatile("s_waitcnt vmcnt(0)" ::: "memory"); \
    BARRIER(); \
} while (0)

__global__ __launch_bounds__(512, 2)
void gemm_mix(const char* __restrict__ Aq,  // qx   M x 4096 i8
              const char* __restrict__ Bq,  // qb   N x 4096 i8
              const char* __restrict__ Ab,  // acts M x 512B bf16
              const char* __restrict__ Bb,  // wob  N x 512B bf16
              const float* __restrict__ rscale,
              const float* __restrict__ cscale,
              const float* __restrict__ bias,
              float* __restrict__ out)
{
    __shared__ __attribute__((aligned(16))) char smem[98304];   // 3 x 32 KB (A only)

    const int tid = threadIdx.x;
    const int wv = tid >> 6, lane = tid & 63;
    const int wm = wv >> 2, wn = wv & 3;
    const int wn1 = wn & 1, whb = wn >> 1;
    const int fr = lane & 15, kq4 = lane >> 4;
    const int rsw = (fr & 7) << 4;               // read-side XOR (bytes)

    // XCD-aware bijective swizzle (512 blocks, 512 % 8 == 0)
    const int bid = blockIdx.x;
    const int lin = (bid & 7) * 64 + (bid >> 3);
    const int bm = (lin & 31) * 256;
    const int bn = (lin >> 5) * 256;

    const int srow = tid >> 3;                   // 0..63
    const int scb  = ((tid & 7) * 16) ^ ((srow & 7) << 4);   // pre-swizzled col

    // per-lane B row base (B row = bn + whb*128 + wn1*64 + n*16 + fr)
    const size_t brow = (size_t)(bn + whb * 128 + wn1 * 64 + fr);
    const char* bqbase = Bq + brow * IN_F + kq4 * 16;
    const char* bbbase = Bb + brow * 512  + kq4 * 16;

    // stage A(T) half h -> LDS buf (global_load_lds; source pre-swizzled)
    auto stA = [&](int T, int h, int buf) {
        const char* src; size_t st;
        if (T < NTI8) { src = Aq + (size_t)(bm + h * 128 + srow) * IN_F
                            + (size_t)T * 128 + scb;            st = IN_F; }
        else          { src = Ab + (size_t)(bm + h * 128 + srow) * 512
                            + (size_t)(T - NTI8) * 128 + scb;   st = 512; }
        char* dst = smem + buf * 32768 + h * 16384 + wv * 1024;
        stage16(src, dst);
        stage16(src + 64 * st, dst + 8192);
    };

    v4i acci[8][4] = {};
    v4i af[4];
    v4i bX[8], bY[8];

    // prologue: A(0)->buf0, A(1)->buf1, b(0)->bX
    stA(0, 0, 0); stA(0, 1, 0);
    stA(1, 0, 1); stA(1, 1, 1);
    BLOAD(0, 0, bX);
    BLOAD(0, 1, bX);
    SB();
    asm volatile("s_waitcnt vmcnt(0)" ::: "memory");
    BARRIER();

    // ---- segment 1: 32 i8 tiles (pairs, static bX/bY roles) ----
    for (int tp = 0; tp < NTI8 / 2; ++tp) {
        const int t0 = tp * 2;
        TILE(t0,     bX, bY, MFMA_I8);
        TILE(t0 + 1, bY, bX, MFMA_I8);
    }

    // exact i32 -> f32 (in-place register reuse; VALU only)
    f32x4 accf[8][4];
    #pragma unroll
    for (int m = 0; m < 8; ++m)
        #pragma unroll
        for (int n = 0; n < 4; ++n) {
            const v4i q = acci[m][n];
            f32x4 f;
            #pragma unroll
            for (int r = 0; r < 4; ++r) f[r] = (float)q[r];
            accf[m][n] = f;
        }

    // ---- segment 2: 4 bf16 tail tiles (b(32) already in bX) ----
    TILE(32, bX, bY, MFMA_BF);
    TILE(33, bY, bX, MFMA_BF);
    TILE(34, bX, bY, MFMA_BF);
    TILE(35, bY, bX, MFMA_BF);

    // epilogue: 16x16 C/D layout col = lane&15, row = (lane>>4)*4 + reg [m89]
    #pragma unroll
    for (int m = 0; m < 8; ++m) {
        const int rbase = bm + wm * 128 + m * 16 + kq4 * 4;
        #pragma unroll
        for (int n = 0; n < 4; ++n) {
            const int col = bn + wn * 64 + n * 16 + fr;
            const float csv = cscale[col];
            const float badd = bias[col];
            #pragma unroll
            for (int r = 0; r < 4; ++r) {
                const int row = rbase + r;
                out[(size_t)row * OUT_F + col] =
                    accf[m][n][r] * rscale[row] * csv + badd;
            }
        }
    }
}

// ---------------------------------------------------------------------------
extern "C" void kernel_launch(void* const* d_in, const int* in_sizes, int n_in,
                              void* d_out, int out_size, void* d_ws, size_t ws_size,
                              hipStream_t stream)
{
    const float* x         = (const float*)d_in[0];
    const int*   q_weight  = (const int*)d_in[1];    // int32 on device
    const float* scale_col = (const float*)d_in[2];
    const float* bias      = (const float*)d_in[3];
    const int*   ind       = (const int*)d_in[4];
    float*       out       = (float*)d_out;

    // workspace (~54 MB)
    char*           qx   = (char*)d_ws;                              // M x IN_F i8
    char*           qb   = qx + (size_t)M_DIM * IN_F;                // OUT_F x IN_F i8
    __hip_bfloat16* acts = (__hip_bfloat16*)(qb + (size_t)OUT_F * IN_F);  // M x NFP
    __hip_bfloat16* wob  = acts + (size_t)M_DIM * NFP;               // OUT_F x NFP
    float*          xs   = (float*)(wob + (size_t)OUT_F * NFP);      // M

    const size_t need = (size_t)((char*)(xs + M_DIM) - (char*)d_ws);
    if (ws_size < need) return;

    quant_rows<<<dim3(M_DIM / 4), dim3(256), 0, stream>>>(x, ind, qx, acts, xs);
    conv_w<<<dim3(OUT_F), dim3(256), 0, stream>>>(q_weight, ind, qb, wob);

    gemm_mix<<<dim3((M_DIM / 256) * (OUT_F / 256)), dim3(512), 0, stream>>>(
        qx, qb, (const char*)acts, (const char*)wob,
        xs, scale_col, bias, out);
}

// Round 12
// 203.130 us; speedup vs baseline: 1.4375x; 1.4375x over previous
//
#include <hip/hip_runtime.h>
#include <hip/hip_bf16.h>
#include <stdint.h>

#define M_DIM 8192
#define IN_F  4096
#define OUT_F 4096
#define NFP   256
#define NTI8  32              // i8 byte-tiles (4096 B / 128 B)
#define NTB   4               // bf16 tail byte-tiles (512 B / 128 B)

typedef __attribute__((ext_vector_type(4)))  int   v4i;
typedef __attribute__((ext_vector_type(8)))  short short8;
typedef __attribute__((ext_vector_type(4)))  float f32x4;

__device__ __forceinline__ void stage16(const void* g, void* l) {
    __builtin_amdgcn_global_load_lds(
        (const __attribute__((address_space(1))) int*)g,
        (__attribute__((address_space(3))) int*)l,
        16, 0, 0);
}

#define SB() __builtin_amdgcn_sched_barrier(0)
#define BARRIER() do { SB(); __builtin_amdgcn_s_barrier(); SB(); } while (0)

// ---------------------------------------------------------------------------
// Kernel 1: per-row quantization, 4 rows per block (amortize omap build).
// ---------------------------------------------------------------------------
__global__ __launch_bounds__(256)
void quant_rows(const float* __restrict__ x,
                const int* __restrict__ ind,
                char* __restrict__ qx,
                __hip_bfloat16* __restrict__ acts,
                float* __restrict__ xscale)
{
    __shared__ short omap[IN_F];
    __shared__ float red[4];
    __shared__ float s_xs;

    const int t = threadIdx.x;

    #pragma unroll
    for (int i = 0; i < IN_F / 256; ++i) omap[t + i * 256] = -1;
    __syncthreads();
    omap[ind[t]] = (short)t;
    __syncthreads();

    short om[16];
    #pragma unroll
    for (int j = 0; j < 16; ++j) om[j] = omap[t * 16 + j];

    for (int r = 0; r < 4; ++r) {
        const int row = blockIdx.x * 4 + r;

        const float* xr = x + (size_t)row * IN_F + t * 16;
        float v[16];
        #pragma unroll
        for (int j = 0; j < 4; ++j) {
            float4 f = *(const float4*)(xr + j * 4);
            v[j*4+0] = f.x; v[j*4+1] = f.y; v[j*4+2] = f.z; v[j*4+3] = f.w;
        }

        float m_nz = 0.f;
        #pragma unroll
        for (int j = 0; j < 16; ++j) {
            float a = fabsf(v[j]);
            if (om[j] < 0) m_nz = fmaxf(m_nz, a);
        }
        #pragma unroll
        for (int off = 32; off > 0; off >>= 1)
            m_nz = fmaxf(m_nz, __shfl_down(m_nz, off));
        if ((t & 63) == 0) red[t >> 6] = m_nz;
        __syncthreads();
        if (t == 0) {
            float a = fmaxf(fmaxf(red[0], red[1]), fmaxf(red[2], red[3]));
            xscale[row] = a / 127.0f;
            s_xs = (a > 0.f) ? (a / 127.0f) : 1.0f;
        }
        __syncthreads();
        const float xs = s_xs;

        union { char c[16]; int4 q; } u;
        #pragma unroll
        for (int j = 0; j < 16; ++j) {
            if (om[j] >= 0) {
                acts[(size_t)row * NFP + om[j]] = __float2bfloat16(v[j] / xs);
                u.c[j] = 0;
            } else {
                float rr = rintf(v[j] / xs);          // half-to-even == jnp.round
                rr = fminf(fmaxf(rr, -128.f), 127.f);
                u.c[j] = (char)(int)rr;
            }
        }
        *(int4*)(qx + (size_t)row * IN_F + t * 16) = u.q;
    }
}

// ---------------------------------------------------------------------------
// Kernel 2: weight int32 -> int8 (exact) + outlier gather (verified).
// ---------------------------------------------------------------------------
__global__ __launch_bounds__(256)
void conv_w(const int* __restrict__ qw, const int* __restrict__ ind,
            char* __restrict__ qb, __hip_bfloat16* __restrict__ wob)
{
    const int n = blockIdx.x;
    const int t = threadIdx.x;
    const int* src = qw + (size_t)n * IN_F + t * 16;
    union { char c[16]; int4 q; } u;
    #pragma unroll
    for (int j = 0; j < 4; ++j) {
        int4 raw = *(const int4*)(src + j * 4);
        u.c[j*4+0] = (char)raw.x; u.c[j*4+1] = (char)raw.y;
        u.c[j*4+2] = (char)raw.z; u.c[j*4+3] = (char)raw.w;
    }
    *(int4*)(qb + (size_t)n * IN_F + t * 16) = u.q;
    wob[(size_t)n * NFP + t] = __float2bfloat16((float)qw[(size_t)n * IN_F + ind[t]]);
}

// ---------------------------------------------------------------------------
// Kernel 3: R10 structure (164us, 41% MfmaUtil) with two changes:
//  (a) post-MFMA barriers of P1,P2 removed (SB keeps order); P3-post kept
//      (guarantees buf-c B-region fully read before P4 stages B(t+2) there);
//      end-of-tile vmcnt+barrier kept. 8 -> 6 barriers/tile.
//  (b) 2D XCD block map: each XCD owns an 8bm x 8bn square.
// Two monomorphic loops: 32 i8 tiles + i32->f32 convert + 4 bf16 tail tiles.
// ---------------------------------------------------------------------------
#define LOADA8(MB, KK) \
    { _Pragma("unroll") for (int i = 0; i < 4; ++i) \
        af[i] = *(const v4i*)&Abuf[(((MB)+i)*16 + fr)*128 + ((((KK)*64) + kq4*16) ^ rsw)]; }
#define LOADB8(KK) \
    { _Pragma("unroll") for (int n = 0; n < 4; ++n) \
        bf4[n] = *(const v4i*)&Bbuf[(wn1*64 + n*16 + fr)*128 + ((((KK)*64) + kq4*16) ^ rsw)]; }
#define MFMA_I8(MB) \
    { _Pragma("unroll") for (int i = 0; i < 4; ++i) \
      _Pragma("unroll") for (int n = 0; n < 4; ++n) \
        acci[(MB)+i][n] = __builtin_amdgcn_mfma_i32_16x16x64_i8(af[i], bf4[n], acci[(MB)+i][n], 0, 0, 0); }

#define LOADAB(MB, KK) \
    { _Pragma("unroll") for (int i = 0; i < 4; ++i) \
        ab[i] = *(const short8*)&Abuf[(((MB)+i)*16 + fr)*128 + ((((KK)*64) + kq4*16) ^ rsw)]; }
#define LOADBB(KK) \
    { _Pragma("unroll") for (int n = 0; n < 4; ++n) \
        bb[n] = *(const short8*)&Bbuf[(wn1*64 + n*16 + fr)*128 + ((((KK)*64) + kq4*16) ^ rsw)]; }
#define MFMA_BF(MB) \
    { _Pragma("unroll") for (int i = 0; i < 4; ++i) \
      _Pragma("unroll") for (int n = 0; n < 4; ++n) \
        accf[(MB)+i][n] = __builtin_amdgcn_mfma_f32_16x16x32_bf16(ab[i], bb[n], accf[(MB)+i][n], 0, 0, 0); }

__global__ __launch_bounds__(512, 2)
void gemm_mix(const char* __restrict__ Aq,  // qx   M x 4096 i8
              const char* __restrict__ Bq,  // qb   N x 4096 i8
              const char* __restrict__ Ab,  // acts M x 512B bf16
              const char* __restrict__ Bb,  // wob  N x 512B bf16
              const float* __restrict__ rscale,
              const float* __restrict__ cscale,
              const float* __restrict__ bias,
              float* __restrict__ out)
{
    __shared__ __attribute__((aligned(16))) char smem[131072];   // 128 KiB

    const int tid = threadIdx.x;
    const int wv = tid >> 6, lane = tid & 63;
    const int wm = wv >> 2, wn = wv & 3;
    const int wn1 = wn & 1, whb = wn >> 1;
    const int fr = lane & 15, kq4 = lane >> 4;
    const int rsw = (fr & 7) << 4;               // read-side XOR (bytes)

    // 2D XCD map: xcd = bid&7 owns an 8bm x 8bn square (bijective, 512 blocks)
    const int bid = blockIdx.x;
    const int xcd = bid & 7, loc = bid >> 3;     // loc in 0..63
    const int bm = ((xcd & 3) * 8 + (loc & 7)) * 256;    // 0..31 tiles
    const int bn = ((xcd >> 2) * 8 + (loc >> 3)) * 256;  // 0..15 tiles

    const int srow = tid >> 3;                   // 0..63
    const int scb  = ((tid & 7) * 16) ^ ((srow & 7) << 4);   // pre-swizzled col

    auto stageA8 = [&](int T, int h, int c) {
        const char* src = Aq + (size_t)(bm + h * 128 + srow) * IN_F + T * 128 + scb;
        char* dst = smem + c * 65536 + h * 16384 + wv * 1024;
        stage16(src, dst);
        stage16(src + (size_t)64 * IN_F, dst + 8192);
    };
    auto stageB8 = [&](int T, int h, int c) {
        const char* src = Bq + (size_t)(bn + h * 128 + srow) * IN_F + T * 128 + scb;
        char* dst = smem + c * 65536 + 32768 + h * 16384 + wv * 1024;
        stage16(src, dst);
        stage16(src + (size_t)64 * IN_F, dst + 8192);
    };
    auto stageAb = [&](int T, int h, int c) {
        const char* src = Ab + (size_t)(bm + h * 128 + srow) * 512 + T * 128 + scb;
        char* dst = smem + c * 65536 + h * 16384 + wv * 1024;
        stage16(src, dst);
        stage16(src + (size_t)64 * 512, dst + 8192);
    };
    auto stageBb = [&](int T, int h, int c) {
        const char* src = Bb + (size_t)(bn + h * 128 + srow) * 512 + T * 128 + scb;
        char* dst = smem + c * 65536 + 32768 + h * 16384 + wv * 1024;
        stage16(src, dst);
        stage16(src + (size_t)64 * 512, dst + 8192);
    };

    // =========================== Loop 1: int8 ===========================
    v4i acci[8][4] = {};
    {
        v4i af[4], bf4[4];

        stageB8(0, 0, 0); stageB8(0, 1, 0);
        stageA8(0, 0, 0); stageA8(0, 1, 0);
        stageB8(1, 0, 1); stageB8(1, 1, 1);
        SB();
        asm volatile("s_waitcnt vmcnt(4)" ::: "memory");
        BARRIER();

        for (int t = 0; t < NTI8; ++t) {
            const int c = t & 1;
            const char* Abuf = smem + c * 65536 + wm * 16384;
            const char* Bbuf = smem + c * 65536 + 32768 + whb * 16384;

            // P1 (reads B k0 + A m0-3 k0; stage A(t+1)h0 -> c^1)
            LOADB8(0);
            LOADA8(0, 0);
            if (t + 1 < NTI8) stageA8(t + 1, 0, c ^ 1);
            BARRIER();
            __builtin_amdgcn_s_setprio(1);
            MFMA_I8(0);
            __builtin_amdgcn_s_setprio(0);
            SB();                                    // (post-barrier removed)
            // P2 (reads A m4-7 k0; stage A(t+1)h1)
            LOADA8(4, 0);
            if (t + 1 < NTI8) stageA8(t + 1, 1, c ^ 1);
            BARRIER();
            __builtin_amdgcn_s_setprio(1);
            MFMA_I8(4);
            __builtin_amdgcn_s_setprio(0);
            SB();                                    // (post-barrier removed)
            // P3 (reads B k1 + A m0-3 k1)
            LOADB8(1);
            LOADA8(0, 1);
            BARRIER();
            __builtin_amdgcn_s_setprio(1);
            MFMA_I8(0);
            __builtin_amdgcn_s_setprio(0);
            BARRIER();           // REQUIRED: buf-c B-region free before P4 stage
            // P4 (reads A m4-7 k1; stage B(t+2) -> buf c)
            LOADA8(4, 1);
            if (t + 2 < NTI8) { stageB8(t + 2, 0, c); stageB8(t + 2, 1, c); }
            BARRIER();
            __builtin_amdgcn_s_setprio(1);
            MFMA_I8(4);
            __builtin_amdgcn_s_setprio(0);
            SB();
            if (t < NTI8 - 2)       asm volatile("s_waitcnt vmcnt(4)" ::: "memory");
            else if (t == NTI8 - 2) asm volatile("s_waitcnt vmcnt(0)" ::: "memory");
            BARRIER();           // end of tile
        }
    }

    // exact i32 -> f32 convert, per fragment
    f32x4 accf[8][4];
    #pragma unroll
    for (int m = 0; m < 8; ++m)
        #pragma unroll
        for (int n = 0; n < 4; ++n) {
            const v4i q = acci[m][n];
            f32x4 f;
            #pragma unroll
            for (int r = 0; r < 4; ++r) f[r] = (float)q[r];
            accf[m][n] = f;
        }

    // ========================== Loop 2: bf16 tail ==========================
    {
        short8 ab[4], bb[4];

        stageBb(0, 0, 0); stageBb(0, 1, 0);
        stageAb(0, 0, 0); stageAb(0, 1, 0);
        stageBb(1, 0, 1); stageBb(1, 1, 1);
        SB();
        asm volatile("s_waitcnt vmcnt(4)" ::: "memory");
        BARRIER();

        for (int t = 0; t < NTB; ++t) {
            const int c = t & 1;
            const char* Abuf = smem + c * 65536 + wm * 16384;
            const char* Bbuf = smem + c * 65536 + 32768 + whb * 16384;

            LOADBB(0);
            LOADAB(0, 0);
            if (t + 1 < NTB) stageAb(t + 1, 0, c ^ 1);
            BARRIER();
            __builtin_amdgcn_s_setprio(1);
            MFMA_BF(0);
            __builtin_amdgcn_s_setprio(0);
            SB();
            LOADAB(4, 0);
            if (t + 1 < NTB) stageAb(t + 1, 1, c ^ 1);
            BARRIER();
            __builtin_amdgcn_s_setprio(1);
            MFMA_BF(4);
            __builtin_amdgcn_s_setprio(0);
            SB();
            LOADBB(1);
            LOADAB(0, 1);
            BARRIER();
            __builtin_amdgcn_s_setprio(1);
            MFMA_BF(0);
            __builtin_amdgcn_s_setprio(0);
            BARRIER();
            LOADAB(4, 1);
            if (t + 2 < NTB) { stageBb(t + 2, 0, c); stageBb(t + 2, 1, c); }
            BARRIER();
            __builtin_amdgcn_s_setprio(1);
            MFMA_BF(4);
            __builtin_amdgcn_s_setprio(0);
            SB();
            if (t < NTB - 2)       asm volatile("s_waitcnt vmcnt(4)" ::: "memory");
            else if (t == NTB - 2) asm volatile("s_waitcnt vmcnt(0)" ::: "memory");
            BARRIER();
        }
    }

    // epilogue: 16x16 C/D layout col = lane&15, row = (lane>>4)*4 + reg [m89]
    #pragma unroll
    for (int m = 0; m < 8; ++m) {
        const int rbase = bm + wm * 128 + m * 16 + kq4 * 4;
        #pragma unroll
        for (int n = 0; n < 4; ++n) {
            const int col = bn + wn * 64 + n * 16 + fr;
            const float csv = cscale[col];
            const float badd = bias[col];
            #pragma unroll
            for (int r = 0; r < 4; ++r) {
                const int row = rbase + r;
                out[(size_t)row * OUT_F + col] =
                    accf[m][n][r] * rscale[row] * csv + badd;
            }
        }
    }
}

// ---------------------------------------------------------------------------
extern "C" void kernel_launch(void* const* d_in, const int* in_sizes, int n_in,
                              void* d_out, int out_size, void* d_ws, size_t ws_size,
                              hipStream_t stream)
{
    const float* x         = (const float*)d_in[0];
    const int*   q_weight  = (const int*)d_in[1];    // int32 on device
    const float* scale_col = (const float*)d_in[2];
    const float* bias      = (const float*)d_in[3];
    const int*   ind       = (const int*)d_in[4];
    float*       out       = (float*)d_out;

    // workspace (~54 MB)
    char*           qx   = (char*)d_ws;                              // M x IN_F i8
    char*           qb   = qx + (size_t)M_DIM * IN_F;                // OUT_F x IN_F i8
    __hip_bfloat16* acts = (__hip_bfloat16*)(qb + (size_t)OUT_F * IN_F);  // M x NFP
    __hip_bfloat16* wob  = acts + (size_t)M_DIM * NFP;               // OUT_F x NFP
    float*          xs   = (float*)(wob + (size_t)OUT_F * NFP);      // M

    const size_t need = (size_t)((char*)(xs + M_DIM) - (char*)d_ws);
    if (ws_size < need) return;

    quant_rows<<<dim3(M_DIM / 4), dim3(256), 0, stream>>>(x, ind, qx, acts, xs);
    conv_w<<<dim3(OUT_F), dim3(256), 0, stream>>>(q_weight, ind, qb, wob);

    gemm_mix<<<dim3((M_DIM / 256) * (OUT_F / 256)), dim3(512), 0, stream>>>(
        qx, qb, (const char*)acts, (const char*)wob,
        xs, scale_col, bias, out);
}

// Round 13
// 202.020 us; speedup vs baseline: 1.4454x; 1.0055x over previous
//
#include <hip/hip_runtime.h>
#include <hip/hip_bf16.h>
#include <stdint.h>

#define M_DIM 8192
#define IN_F  4096
#define OUT_F 4096
#define NFP   256
#define NTI8  32              // i8 byte-tiles (4096 B / 128 B)
#define NTB   4               // bf16 tail byte-tiles (512 B / 128 B)

typedef __attribute__((ext_vector_type(4)))  int   v4i;
typedef __attribute__((ext_vector_type(8)))  short short8;
typedef __attribute__((ext_vector_type(4)))  float f32x4;

__device__ __forceinline__ void stage16(const void* g, void* l) {
    __builtin_amdgcn_global_load_lds(
        (const __attribute__((address_space(1))) int*)g,
        (__attribute__((address_space(3))) int*)l,
        16, 0, 0);
}

#define SB() __builtin_amdgcn_sched_barrier(0)
#define BARRIER() do { SB(); __builtin_amdgcn_s_barrier(); SB(); } while (0)

// ---------------------------------------------------------------------------
// Kernel 1: per-row quantization, 4 rows per block (verified R12).
// ---------------------------------------------------------------------------
__global__ __launch_bounds__(256)
void quant_rows(const float* __restrict__ x,
                const int* __restrict__ ind,
                char* __restrict__ qx,
                __hip_bfloat16* __restrict__ acts,
                float* __restrict__ xscale)
{
    __shared__ short omap[IN_F];
    __shared__ float red[4];
    __shared__ float s_xs;

    const int t = threadIdx.x;

    #pragma unroll
    for (int i = 0; i < IN_F / 256; ++i) omap[t + i * 256] = -1;
    __syncthreads();
    omap[ind[t]] = (short)t;
    __syncthreads();

    short om[16];
    #pragma unroll
    for (int j = 0; j < 16; ++j) om[j] = omap[t * 16 + j];

    for (int r = 0; r < 4; ++r) {
        const int row = blockIdx.x * 4 + r;

        const float* xr = x + (size_t)row * IN_F + t * 16;
        float v[16];
        #pragma unroll
        for (int j = 0; j < 4; ++j) {
            float4 f = *(const float4*)(xr + j * 4);
            v[j*4+0] = f.x; v[j*4+1] = f.y; v[j*4+2] = f.z; v[j*4+3] = f.w;
        }

        float m_nz = 0.f;
        #pragma unroll
        for (int j = 0; j < 16; ++j) {
            float a = fabsf(v[j]);
            if (om[j] < 0) m_nz = fmaxf(m_nz, a);
        }
        #pragma unroll
        for (int off = 32; off > 0; off >>= 1)
            m_nz = fmaxf(m_nz, __shfl_down(m_nz, off));
        if ((t & 63) == 0) red[t >> 6] = m_nz;
        __syncthreads();
        if (t == 0) {
            float a = fmaxf(fmaxf(red[0], red[1]), fmaxf(red[2], red[3]));
            xscale[row] = a / 127.0f;
            s_xs = (a > 0.f) ? (a / 127.0f) : 1.0f;
        }
        __syncthreads();
        const float xs = s_xs;

        union { char c[16]; int4 q; } u;
        #pragma unroll
        for (int j = 0; j < 16; ++j) {
            if (om[j] >= 0) {
                acts[(size_t)row * NFP + om[j]] = __float2bfloat16(v[j] / xs);
                u.c[j] = 0;
            } else {
                float rr = rintf(v[j] / xs);          // half-to-even == jnp.round
                rr = fminf(fmaxf(rr, -128.f), 127.f);
                u.c[j] = (char)(int)rr;
            }
        }
        *(int4*)(qx + (size_t)row * IN_F + t * 16) = u.q;
    }
}

// ---------------------------------------------------------------------------
// Kernel 2: weight int32 -> int8 (exact) + outlier gather (verified).
// ---------------------------------------------------------------------------
__global__ __launch_bounds__(256)
void conv_w(const int* __restrict__ qw, const int* __restrict__ ind,
            char* __restrict__ qb, __hip_bfloat16* __restrict__ wob)
{
    const int n = blockIdx.x;
    const int t = threadIdx.x;
    const int* src = qw + (size_t)n * IN_F + t * 16;
    union { char c[16]; int4 q; } u;
    #pragma unroll
    for (int j = 0; j < 4; ++j) {
        int4 raw = *(const int4*)(src + j * 4);
        u.c[j*4+0] = (char)raw.x; u.c[j*4+1] = (char)raw.y;
        u.c[j*4+2] = (char)raw.z; u.c[j*4+3] = (char)raw.w;
    }
    *(int4*)(qb + (size_t)n * IN_F + t * 16) = u.q;
    wob[(size_t)n * NFP + t] = __float2bfloat16((float)qw[(size_t)n * IN_F + ind[t]]);
}

// ---------------------------------------------------------------------------
// Kernel 3: R12 structure (150us, 45% MfmaUtil, FETCH 110MB) with ONE change:
// 6 -> 2 barriers/tile. Hazard audit: buffer c is stable within a tile, so
// pre-MFMA barriers are choreography only. Kept barriers:
//  (1) mid-tile, after the k1/m0-3 MFMA: every wave's B-reads of buf c are
//      consumed (lgkm-waited) by its preceding MFMAs -> after this barrier,
//      staging B(t+2) into buf c's B-region is safe;
//  (2) end-of-tile after counted vmcnt(4): A(t+1) (4 older stages) drained,
//      B(t+2) (4 newer) left in flight.
// Waves free-run inside the tile -> ds_read / MFMA overlap across waves.
// Stages issued at region top (issue-early, T14).
// ---------------------------------------------------------------------------
#define LOADA8(MB, KK) \
    { _Pragma("unroll") for (int i = 0; i < 4; ++i) \
        af[i] = *(const v4i*)&Abuf[(((MB)+i)*16 + fr)*128 + ((((KK)*64) + kq4*16) ^ rsw)]; }
#define LOADB8(KK) \
    { _Pragma("unroll") for (int n = 0; n < 4; ++n) \
        bf4[n] = *(const v4i*)&Bbuf[(wn1*64 + n*16 + fr)*128 + ((((KK)*64) + kq4*16) ^ rsw)]; }
#define MFMA_I8(MB) \
    { _Pragma("unroll") for (int i = 0; i < 4; ++i) \
      _Pragma("unroll") for (int n = 0; n < 4; ++n) \
        acci[(MB)+i][n] = __builtin_amdgcn_mfma_i32_16x16x64_i8(af[i], bf4[n], acci[(MB)+i][n], 0, 0, 0); }

#define LOADAB(MB, KK) \
    { _Pragma("unroll") for (int i = 0; i < 4; ++i) \
        ab[i] = *(const short8*)&Abuf[(((MB)+i)*16 + fr)*128 + ((((KK)*64) + kq4*16) ^ rsw)]; }
#define LOADBB(KK) \
    { _Pragma("unroll") for (int n = 0; n < 4; ++n) \
        bb[n] = *(const short8*)&Bbuf[(wn1*64 + n*16 + fr)*128 + ((((KK)*64) + kq4*16) ^ rsw)]; }
#define MFMA_BF(MB) \
    { _Pragma("unroll") for (int i = 0; i < 4; ++i) \
      _Pragma("unroll") for (int n = 0; n < 4; ++n) \
        accf[(MB)+i][n] = __builtin_amdgcn_mfma_f32_16x16x32_bf16(ab[i], bb[n], accf[(MB)+i][n], 0, 0, 0); }

__global__ __launch_bounds__(512, 2)
void gemm_mix(const char* __restrict__ Aq,  // qx   M x 4096 i8
              const char* __restrict__ Bq,  // qb   N x 4096 i8
              const char* __restrict__ Ab,  // acts M x 512B bf16
              const char* __restrict__ Bb,  // wob  N x 512B bf16
              const float* __restrict__ rscale,
              const float* __restrict__ cscale,
              const float* __restrict__ bias,
              float* __restrict__ out)
{
    __shared__ __attribute__((aligned(16))) char smem[131072];   // 128 KiB

    const int tid = threadIdx.x;
    const int wv = tid >> 6, lane = tid & 63;
    const int wm = wv >> 2, wn = wv & 3;
    const int wn1 = wn & 1, whb = wn >> 1;
    const int fr = lane & 15, kq4 = lane >> 4;
    const int rsw = (fr & 7) << 4;               // read-side XOR (bytes)

    // 2D XCD map: xcd = bid&7 owns an 8bm x 8bn square (bijective, 512 blocks)
    const int bid = blockIdx.x;
    const int xcd = bid & 7, loc = bid >> 3;     // loc in 0..63
    const int bm = ((xcd & 3) * 8 + (loc & 7)) * 256;    // 0..31 tiles
    const int bn = ((xcd >> 2) * 8 + (loc >> 3)) * 256;  // 0..15 tiles

    const int srow = tid >> 3;                   // 0..63
    const int scb  = ((tid & 7) * 16) ^ ((srow & 7) << 4);   // pre-swizzled col

    auto stageA8 = [&](int T, int h, int c) {
        const char* src = Aq + (size_t)(bm + h * 128 + srow) * IN_F + T * 128 + scb;
        char* dst = smem + c * 65536 + h * 16384 + wv * 1024;
        stage16(src, dst);
        stage16(src + (size_t)64 * IN_F, dst + 8192);
    };
    auto stageB8 = [&](int T, int h, int c) {
        const char* src = Bq + (size_t)(bn + h * 128 + srow) * IN_F + T * 128 + scb;
        char* dst = smem + c * 65536 + 32768 + h * 16384 + wv * 1024;
        stage16(src, dst);
        stage16(src + (size_t)64 * IN_F, dst + 8192);
    };
    auto stageAb = [&](int T, int h, int c) {
        const char* src = Ab + (size_t)(bm + h * 128 + srow) * 512 + T * 128 + scb;
        char* dst = smem + c * 65536 + h * 16384 + wv * 1024;
        stage16(src, dst);
        stage16(src + (size_t)64 * 512, dst + 8192);
    };
    auto stageBb = [&](int T, int h, int c) {
        const char* src = Bb + (size_t)(bn + h * 128 + srow) * 512 + T * 128 + scb;
        char* dst = smem + c * 65536 + 32768 + h * 16384 + wv * 1024;
        stage16(src, dst);
        stage16(src + (size_t)64 * 512, dst + 8192);
    };

    // =========================== Loop 1: int8 ===========================
    v4i acci[8][4] = {};
    {
        v4i af[4], bf4[4];

        stageB8(0, 0, 0); stageB8(0, 1, 0);
        stageA8(0, 0, 0); stageA8(0, 1, 0);
        stageB8(1, 0, 1); stageB8(1, 1, 1);
        SB();
        asm volatile("s_waitcnt vmcnt(4)" ::: "memory");
        BARRIER();

        for (int t = 0; t < NTI8; ++t) {
            const int c = t & 1;
            const char* Abuf = smem + c * 65536 + wm * 16384;
            const char* Bbuf = smem + c * 65536 + 32768 + whb * 16384;

            // ---- free-run region 1: A(t+1) stages + k0 compute + k1/m0-3 ----
            if (t + 1 < NTI8) { stageA8(t + 1, 0, c ^ 1); stageA8(t + 1, 1, c ^ 1); }
            LOADB8(0);
            LOADA8(0, 0);
            __builtin_amdgcn_s_setprio(1);
            MFMA_I8(0);
            __builtin_amdgcn_s_setprio(0);
            LOADA8(4, 0);
            __builtin_amdgcn_s_setprio(1);
            MFMA_I8(4);
            __builtin_amdgcn_s_setprio(0);
            LOADB8(1);
            LOADA8(0, 1);
            __builtin_amdgcn_s_setprio(1);
            MFMA_I8(0);
            __builtin_amdgcn_s_setprio(0);
            BARRIER();   // all waves consumed their B-reads of buf c
            // ---- region 2: stage B(t+2) into freed B-region + k1/m4-7 ----
            LOADA8(4, 1);
            if (t + 2 < NTI8) { stageB8(t + 2, 0, c); stageB8(t + 2, 1, c); }
            __builtin_amdgcn_s_setprio(1);
            MFMA_I8(4);
            __builtin_amdgcn_s_setprio(0);
            SB();
            if (t < NTI8 - 2)       asm volatile("s_waitcnt vmcnt(4)" ::: "memory");
            else if (t == NTI8 - 2) asm volatile("s_waitcnt vmcnt(0)" ::: "memory");
            BARRIER();   // end of tile: t+1 buffers ready
        }
    }

    // exact i32 -> f32 convert, per fragment
    f32x4 accf[8][4];
    #pragma unroll
    for (int m = 0; m < 8; ++m)
        #pragma unroll
        for (int n = 0; n < 4; ++n) {
            const v4i q = acci[m][n];
            f32x4 f;
            #pragma unroll
            for (int r = 0; r < 4; ++r) f[r] = (float)q[r];
            accf[m][n] = f;
        }

    // ========================== Loop 2: bf16 tail ==========================
    {
        short8 ab[4], bb[4];

        stageBb(0, 0, 0); stageBb(0, 1, 0);
        stageAb(0, 0, 0); stageAb(0, 1, 0);
        stageBb(1, 0, 1); stageBb(1, 1, 1);
        SB();
        asm volatile("s_waitcnt vmcnt(4)" ::: "memory");
        BARRIER();

        for (int t = 0; t < NTB; ++t) {
            const int c = t & 1;
            const char* Abuf = smem + c * 65536 + wm * 16384;
            const char* Bbuf = smem + c * 65536 + 32768 + whb * 16384;

            if (t + 1 < NTB) { stageAb(t + 1, 0, c ^ 1); stageAb(t + 1, 1, c ^ 1); }
            LOADBB(0);
            LOADAB(0, 0);
            __builtin_amdgcn_s_setprio(1);
            MFMA_BF(0);
            __builtin_amdgcn_s_setprio(0);
            LOADAB(4, 0);
            __builtin_amdgcn_s_setprio(1);
            MFMA_BF(4);
            __builtin_amdgcn_s_setprio(0);
            LOADBB(1);
            LOADAB(0, 1);
            __builtin_amdgcn_s_setprio(1);
            MFMA_BF(0);
            __builtin_amdgcn_s_setprio(0);
            BARRIER();
            LOADAB(4, 1);
            if (t + 2 < NTB) { stageBb(t + 2, 0, c); stageBb(t + 2, 1, c); }
            __builtin_amdgcn_s_setprio(1);
            MFMA_BF(4);
            __builtin_amdgcn_s_setprio(0);
            SB();
            if (t < NTB - 2)       asm volatile("s_waitcnt vmcnt(4)" ::: "memory");
            else if (t == NTB - 2) asm volatile("s_waitcnt vmcnt(0)" ::: "memory");
            BARRIER();
        }
    }

    // epilogue: 16x16 C/D layout col = lane&15, row = (lane>>4)*4 + reg [m89]
    #pragma unroll
    for (int m = 0; m < 8; ++m) {
        const int rbase = bm + wm * 128 + m * 16 + kq4 * 4;
        #pragma unroll
        for (int n = 0; n < 4; ++n) {
            const int col = bn + wn * 64 + n * 16 + fr;
            const float csv = cscale[col];
            const float badd = bias[col];
            #pragma unroll
            for (int r = 0; r < 4; ++r) {
                const int row = rbase + r;
                out[(size_t)row * OUT_F + col] =
                    accf[m][n][r] * rscale[row] * csv + badd;
            }
        }
    }
}

// ---------------------------------------------------------------------------
extern "C" void kernel_launch(void* const* d_in, const int* in_sizes, int n_in,
                              void* d_out, int out_size, void* d_ws, size_t ws_size,
                              hipStream_t stream)
{
    const float* x         = (const float*)d_in[0];
    const int*   q_weight  = (const int*)d_in[1];    // int32 on device
    const float* scale_col = (const float*)d_in[2];
    const float* bias      = (const float*)d_in[3];
    const int*   ind       = (const int*)d_in[4];
    float*       out       = (float*)d_out;

    // workspace (~54 MB)
    char*           qx   = (char*)d_ws;                              // M x IN_F i8
    char*           qb   = qx + (size_t)M_DIM * IN_F;                // OUT_F x IN_F i8
    __hip_bfloat16* acts = (__hip_bfloat16*)(qb + (size_t)OUT_F * IN_F);  // M x NFP
    __hip_bfloat16* wob  = acts + (size_t)M_DIM * NFP;               // OUT_F x NFP
    float*          xs   = (float*)(wob + (size_t)OUT_F * NFP);      // M

    const size_t need = (size_t)((char*)(xs + M_DIM) - (char*)d_ws);
    if (ws_size < need) return;

    quant_rows<<<dim3(M_DIM / 4), dim3(256), 0, stream>>>(x, ind, qx, acts, xs);
    conv_w<<<dim3(OUT_F), dim3(256), 0, stream>>>(q_weight, ind, qb, wob);

    gemm_mix<<<dim3((M_DIM / 256) * (OUT_F / 256)), dim3(512), 0, stream>>>(
        qx, qb, (const char*)acts, (const char*)wob,
        xs, scale_col, bias, out);
}